// Round 4
// baseline (149.064 us; speedup 1.0000x reference)
//
#include <hip/hip_runtime.h>
#include <hip/hip_bf16.h>
#include <hip/hip_fp8.h>
#include <cstdint>
#include <cstddef>

// Problem constants (x = (8192, 768) fp32)
#define GN 8192
#define GD 768           // elements per row; fp8 => 768 bytes per row
#define NB 64            // 128-row blocks
#define NTILE 2080       // NB*(NB+1)/2 triangular tiles
#define KI 12            // 768 / 64 : K-iterations, 64 bytes (one 32x32x64 MFMA) each

#define LOG2E 1.4426950408889634f
#define LN2 0.6931471805599453f

typedef __attribute__((ext_vector_type(4))) float f32x4;
typedef __attribute__((ext_vector_type(16))) float f32x16;
typedef __attribute__((ext_vector_type(4))) int i32x4;
typedef __attribute__((ext_vector_type(8))) int i32x8;

typedef __attribute__((address_space(1))) const unsigned int gu32;
typedef __attribute__((address_space(3))) unsigned int lu32;

#define SHUF8(L, H) __builtin_shufflevector(L, H, 0, 1, 2, 3, 4, 5, 6, 7)
#define Z16 {0.f, 0.f, 0.f, 0.f, 0.f, 0.f, 0.f, 0.f, 0.f, 0.f, 0.f, 0.f, 0.f, 0.f, 0.f, 0.f}
#define MXFMA(A, B, C) __builtin_amdgcn_mfma_scale_f32_32x32x64_f8f6f4( \
    A, B, C, 0, 0, 0, 0x7f7f7f7f, 0, 0x7f7f7f7f)

__device__ __forceinline__ void gl2lds16(const void* g, void* l) {
    // async global->LDS, 16B per lane; LDS dest is wave-uniform base + lane*16
    __builtin_amdgcn_global_load_lds((gu32*)g, (lu32*)l, 16, 0, 0);
}

__device__ __forceinline__ float hexp2(float x) {
    return __builtin_amdgcn_exp2f(x);
}

// DPP rotate within each 16-lane row (VALU pipe, not DS): dpp_ctrl = 0x120|n.
template <int CTRL>
__device__ __forceinline__ float fdpp(float x) {
    return __int_as_float(__builtin_amdgcn_update_dpp(
        0, __float_as_int(x), CTRL, 0xF, 0xF, true));
}
__device__ __forceinline__ float qmax16(float v) {
    v = fmaxf(v, fdpp<0x128>(v));  // row_ror:8
    v = fmaxf(v, fdpp<0x124>(v));  // row_ror:4
    v = fmaxf(v, fdpp<0x122>(v));  // row_ror:2
    v = fmaxf(v, fdpp<0x121>(v));  // row_ror:1
    return v;
}
__device__ __forceinline__ float qsum16(float v) {
    v += fdpp<0x128>(v);
    v += fdpp<0x124>(v);
    v += fdpp<0x122>(v);
    v += fdpp<0x121>(v);
    return v;
}

// ---------------- Kernel 1: fp8 e4m3 quantize + row sum-of-squares of the
// DEQUANTIZED values (sim_ij = -||x^_i - x^_j||^2 - 100*diag exactly) -------
__global__ __launch_bounds__(256) void prep_kernel(const float* __restrict__ x,
                                                   unsigned char* __restrict__ xq,
                                                   float* __restrict__ sq,
                                                   float* __restrict__ out) {
    if (blockIdx.x == 0 && threadIdx.x == 0) out[0] = 0.f;  // for combine's atomics
    const int w = threadIdx.x >> 6, lane = threadIdx.x & 63;
    const int row = blockIdx.x * 4 + w;
    const float4* xr = (const float4*)(x + (size_t)row * GD);
    unsigned int* xqr = (unsigned int*)(xq + (size_t)row * GD);
    float s = 0.f;
#pragma unroll
    for (int i = 0; i < 3; ++i) {
        float4 v = xr[lane + 64 * i];
        unsigned int pk = __builtin_amdgcn_cvt_pk_fp8_f32(v.x, v.y, 0, false);
        pk = __builtin_amdgcn_cvt_pk_fp8_f32(v.z, v.w, pk, true);
        float d0 = __builtin_amdgcn_cvt_f32_fp8(pk, 0);
        float d1 = __builtin_amdgcn_cvt_f32_fp8(pk, 1);
        float d2 = __builtin_amdgcn_cvt_f32_fp8(pk, 2);
        float d3 = __builtin_amdgcn_cvt_f32_fp8(pk, 3);
        s += d0 * d0 + d1 * d1 + d2 * d2 + d3 * d3;
        xqr[lane + 64 * i] = pk;
    }
#pragma unroll
    for (int off = 1; off < 64; off <<= 1) s += __shfl_xor(s, off);
    if (lane == 0) sq[row] = s;
}

// ------- Kernel 2: symmetric triangular tile GEMM (MX-fp8, scale=1.0) + entropy -------
// Round-3 post-mortem: 4.28e6 bank conflicts (22x round-0) -- lanes l and l+16
// had IDENTICAL LDS slots under the old swizzle with the 32-row read pattern
// (conflict under the {l,l+16,l+32,l+48} crossbar phase grouping implied by the
// round-0-vs-round-3 measurements). Round-4 changes:
//  (a) NEW B layout: per 32-row group (2KB), granule (r,q) at slot
//      s = (qlo<<6)|(qhi<<5)|(r4<<4)|(r3<<3)|((r&7)^((qhi<<1)|r4)), addr=s*16.
//      Bank bits distinct within every quad {l,l+16,l+32,l+48} AND every 8
//      consecutive lanes. Staged via inverse-permuted global source.
//  (b) A fragments bypass LDS entirely (no cross-wave reuse): direct
//      global->register, double-buffered one K-iter ahead. LDS = 16KB (B only).
// 32x32x64 operand layout (HW-verified): A/B row = lane&31, k-half = lane>>5
// -> granules {2*hi, 2*hi+1}. C/D: col = lane&31, reg e -> row =
// (e&3) + 8*(e>>2) + 4*(lane>>5).
__global__ __launch_bounds__(256, 3) void sym_gemm_entropy(
    const unsigned char* __restrict__ xq, const float* __restrict__ sq,
    const float* __restrict__ taup, float* __restrict__ pm,
    float* __restrict__ ps, float* __restrict__ pt) {
    __shared__ __align__(16) char lds[16384];  // [B0 8K][B1 8K]
    float (*tmrg)[4][3] = (float (*)[4][3])lds;  // aliased; guarded by barrier

    const int tid = threadIdx.x;
    const int lane = tid & 63;
    const int w = tid >> 6;
    const int cl2 = lane & 31, hi = lane >> 5;

    const int b = blockIdx.x;
    int I = (int)((sqrtf(8.0f * (float)b + 1.0f) - 1.0f) * 0.5f);
    while ((I + 1) * (I + 2) / 2 <= b) ++I;
    while (I * (I + 1) / 2 > b) --I;
    const int J = b - I * (I + 1) / 2;
    const int row_base = I * 128;
    const int col_base = J * 128;
    const float taub = (*taup) * LOG2E;  // base-2 scale

    // ---- B staging decode: thread t fills slot (t&127) of group (t>>7) ----
    {
    }
    const int sS = tid & 127;
    const int ggS = tid >> 7;                     // 0/1: which 32-row group in this call
    const int qloS = (sS >> 6) & 1, qhiS = (sS >> 5) & 1;
    const int r4S = (sS >> 4) & 1, r3S = (sS >> 3) & 1;
    const int rlowS = (sS & 7) ^ ((qhiS << 1) | r4S);
    const int rB = ggS * 32 + ((r4S << 4) | (r3S << 3) | rlowS);  // 0..63
    const int qB = (qhiS << 1) | qloS;                            // granule 0..3
    const unsigned char* gB = xq + (size_t)(col_base + rB) * GD + qB * 16;

    // ---- B fragment read offsets (new layout; named scalars) ----
    const int r4L = (cl2 >> 4) & 1, r3L = (cl2 >> 3) & 1;
    const int bsl = (cl2 & 7) ^ ((hi << 1) | r4L);
    const int s0 = (hi << 5) | (r4L << 4) | (r3L << 3) | bsl;  // qlo=0 slot
    const int offB00 = 0 * 2048 + (s0 << 4), offB01 = offB00 + 1024;  // qlo=1: +64 slots
    const int offB10 = 1 * 2048 + (s0 << 4), offB11 = offB10 + 1024;
    const int offB20 = 2 * 2048 + (s0 << 4), offB21 = offB20 + 1024;
    const int offB30 = 3 * 2048 + (s0 << 4), offB31 = offB30 + 1024;

    // ---- A: direct global->register (row = row_base + w*32 + cl2) ----
    const unsigned char* gAr =
        xq + (size_t)(row_base + w * 32 + cl2) * GD + 32 * hi;

    f32x16 acc0 = Z16, acc1 = Z16, acc2 = Z16, acc3 = Z16;

    // prologue: stage B k=0 into buffer 0; load A k=0 into registers
    gl2lds16(gB, lds + tid * 16);
    gl2lds16(gB + (size_t)64 * GD, lds + 4096 + tid * 16);
    i32x4 aCL = *(const i32x4*)(gAr);
    i32x4 aCH = *(const i32x4*)(gAr + 16);
    i32x4 aNL = aCL, aNH = aCH;

#pragma unroll 2
    for (int kk = 0; kk < KI; ++kk) {
        __syncthreads();  // B buf[kk&1] staged; prior buf's ds_reads done

        // 1) read the 8 B fragments of this iter (8 x ds_read_b128)
        const char* Bb = lds + (kk & 1) * 8192;
        i32x4 b0L = *(const i32x4*)(Bb + offB00), b0H = *(const i32x4*)(Bb + offB01);
        i32x4 b1L = *(const i32x4*)(Bb + offB10), b1H = *(const i32x4*)(Bb + offB11);
        i32x4 b2L = *(const i32x4*)(Bb + offB20), b2H = *(const i32x4*)(Bb + offB21);
        i32x4 b3L = *(const i32x4*)(Bb + offB30), b3H = *(const i32x4*)(Bb + offB31);

        // 2) stage B k+1 into the other buffer; prefetch A k+1 to registers
        if (kk + 1 < KI) {
            char* Bn = lds + ((kk + 1) & 1) * 8192;
            const int ko = (kk + 1) * 64;  // bytes along K
            gl2lds16(gB + ko, Bn + tid * 16);
            gl2lds16(gB + (size_t)64 * GD + ko, Bn + 4096 + tid * 16);
            aNL = *(const i32x4*)(gAr + ko);
            aNH = *(const i32x4*)(gAr + ko + 16);
        }

        // 3) 4 MX MFMAs (K=64, fmt fp8/fp8, scales = 1.0 -> exact fp8 GEMM)
        i32x8 av = SHUF8(aCL, aCH);
        acc0 = MXFMA(av, SHUF8(b0L, b0H), acc0);
        acc1 = MXFMA(av, SHUF8(b1L, b1H), acc1);
        acc2 = MXFMA(av, SHUF8(b2L, b2H), acc2);
        acc3 = MXFMA(av, SHUF8(b3L, b3H), acc3);

        aCL = aNL;
        aCH = aNH;
    }

    // ---- split named f32x16 accs into f32x4 quads (constant masks only) ----
    f32x4 pa[4][4];
#define SPLIT16(TJ, A)                                          \
    pa[TJ][0] = __builtin_shufflevector(A, A, 0, 1, 2, 3);      \
    pa[TJ][1] = __builtin_shufflevector(A, A, 4, 5, 6, 7);      \
    pa[TJ][2] = __builtin_shufflevector(A, A, 8, 9, 10, 11);    \
    pa[TJ][3] = __builtin_shufflevector(A, A, 12, 13, 14, 15);
    SPLIT16(0, acc0)
    SPLIT16(1, acc1)
    SPLIT16(2, acc2)
    SPLIT16(3, acc3)
#undef SPLIT16

    // ---------------- epilogue (base-2 state, base-cancelled deltas) ----------------
    const float t2 = 2.f * taub;
    const float pen = 100.f * taub;
    float ar[16];  // -taub * sq[row], indexed [q*4+rg]
#pragma unroll
    for (int q = 0; q < 4; ++q)
#pragma unroll
        for (int rg = 0; rg < 4; ++rg)
            ar[q * 4 + rg] = -taub * sq[row_base + w * 32 + rg + 8 * q + 4 * hi];
    float ac[4];  // -taub * sq[col] for this lane's 4 cols
#pragma unroll
    for (int tj = 0; tj < 4; ++tj) ac[tj] = -taub * sq[col_base + tj * 32 + cl2];

    float* pmJ = pm + (size_t)J * GN;
    float* psJ = ps + (size_t)J * GN;
    float* ptJ = pt + (size_t)J * GN;

    // ---- direct pass: reduce over cols (4 tj in-thread x 32 lanes); the row
    // term is uniform across the reduction -> cancels in d; added once to m ----
#pragma unroll
    for (int q = 0; q < 4; ++q)
#pragma unroll
        for (int rg = 0; rg < 4; ++rg) {
            const int rl = rg + 8 * q + 4 * hi;
            const int rglob = row_base + w * 32 + rl;
            float uu[4];
            float mloc = -1e30f;
            if (I == J) {  // block-uniform: only diagonal tiles carry the penalty
#pragma unroll
                for (int tj = 0; tj < 4; ++tj) {
                    float u = fmaf(t2, pa[tj][q][rg], ac[tj]);
                    if (rglob == col_base + tj * 32 + cl2) u -= pen;
                    uu[tj] = u;
                    mloc = fmaxf(mloc, u);
                }
            } else {
#pragma unroll
                for (int tj = 0; tj < 4; ++tj) {
                    float u = fmaf(t2, pa[tj][q][rg], ac[tj]);
                    uu[tj] = u;
                    mloc = fmaxf(mloc, u);
                }
            }
            mloc = fmaxf(mloc, __shfl_xor(mloc, 16));  // 32-wide max
            mloc = qmax16(mloc);
            float s = 0.f, t = 0.f;
#pragma unroll
            for (int tj = 0; tj < 4; ++tj) {
                float d = uu[tj] - mloc;  // row term cancelled
                float e = hexp2(d);       // bare v_exp_f32
                s += e;
                t += e * d;
            }
            s += __shfl_xor(s, 16);
            t += __shfl_xor(t, 16);
            s = qsum16(s);
            t = qsum16(t);
            if (cl2 == 0) {  // lanes 0 and 32 write disjoint rows
                pmJ[rglob] = mloc + ar[q * 4 + rg];  // base restored once
                psJ[rglob] = s;
                ptJ[rglob] = t;
            }
        }

    // ---- transposed pass: reduce over rows (16 in-thread x 2 hi-halves); col
    // term uniform across the reduction -> cancels in d; added once to m ----
    if (I != J) {  // block-uniform branch
        __syncthreads();  // all K-loop LDS reads done before tmrg aliases the buffer
#pragma unroll
        for (int tj = 0; tj < 4; ++tj) {
            float uu[16];
            float mloc = -1e30f;
#pragma unroll
            for (int q = 0; q < 4; ++q)
#pragma unroll
                for (int rg = 0; rg < 4; ++rg) {
                    float u = fmaf(t2, pa[tj][q][rg], ar[q * 4 + rg]);
                    uu[q * 4 + rg] = u;
                    mloc = fmaxf(mloc, u);
                }
            mloc = fmaxf(mloc, __shfl_xor(mloc, 32));  // combine hi-halves
            float s = 0.f, t = 0.f;
#pragma unroll
            for (int k = 0; k < 16; ++k) {
                float d = uu[k] - mloc;
                float e = hexp2(d);
                s += e;
                t += e * d;
            }
            s += __shfl_xor(s, 32);
            t += __shfl_xor(t, 32);
            if (hi == 0) {
                int c = tj * 32 + cl2;
                tmrg[c][w][0] = mloc + ac[tj];  // col term restored once
                tmrg[c][w][1] = s;
                tmrg[c][w][2] = t;
            }
        }
        __syncthreads();
        if (tid < 128) {
            float m = tmrg[tid][0][0], S = tmrg[tid][0][1], T = tmrg[tid][0][2];
#pragma unroll
            for (int ww = 1; ww < 4; ++ww) {
                float mc = tmrg[tid][ww][0], Sc = tmrg[tid][ww][1], Tc = tmrg[tid][ww][2];
                float mn = fmaxf(m, mc);
                float ea = hexp2(m - mn), eb = hexp2(mc - mn);
                T = (T + (m - mn) * S) * ea + (Tc + (mc - mn) * Sc) * eb;
                S = S * ea + Sc * eb;
                m = mn;
            }
            int c = col_base + tid;
            pm[(size_t)I * GN + c] = m;
            ps[(size_t)I * GN + c] = S;
            pt[(size_t)I * GN + c] = T;
        }
    }
}

// ------- Kernel 3: combine (base-2), coalesced + parallel -------
__global__ __launch_bounds__(256) void combine(const float* __restrict__ pm,
                                               const float* __restrict__ ps,
                                               const float* __restrict__ pt,
                                               const float* __restrict__ coefp,
                                               float* __restrict__ out) {
    const int t = threadIdx.x;
    const int r = t & 63;
    const int chunk = t >> 6;
    const int row = blockIdx.x * 64 + r;
    float m = -1e30f, S = 0.f, T = 0.f;
#pragma unroll
    for (int i = 0; i < 16; ++i) {
        const int c = chunk * 16 + i;
        float mc = pm[(size_t)c * GN + row];
        float Sc = ps[(size_t)c * GN + row];
        float Tc = pt[(size_t)c * GN + row];
        float mn = fmaxf(m, mc);
        float ea = __builtin_amdgcn_exp2f(m - mn), eb = __builtin_amdgcn_exp2f(mc - mn);
        T = (T + (m - mn) * S) * ea + (Tc + (mc - mn) * Sc) * eb;
        S = S * ea + Sc * eb;
        m = mn;
    }
    __shared__ float lm[4][64], lS[4][64], lT[4][64];
    lm[chunk][r] = m;
    lS[chunk][r] = S;
    lT[chunk][r] = T;
    __syncthreads();
    if (t < 64) {
        float M = lm[0][r], Sa = lS[0][r], Ta = lT[0][r];
#pragma unroll
        for (int cc = 1; cc < 4; ++cc) {
            float mc = lm[cc][r], Sc = lS[cc][r], Tc = lT[cc][r];
            float mn = fmaxf(M, mc);
            float ea = __builtin_amdgcn_exp2f(M - mn), eb = __builtin_amdgcn_exp2f(mc - mn);
            Ta = (Ta + (M - mn) * Sa) * ea + (Tc + (mc - mn) * Sc) * eb;
            Sa = Sa * ea + Sc * eb;
            M = mn;
        }
        float ent2 = __log2f(Sa) - Ta / Sa;  // base-2 row entropy (v_log_f32)
#pragma unroll
        for (int off = 1; off < 64; off <<= 1) ent2 += __shfl_xor(ent2, off);
        if (t == 0) atomicAdd(out, ent2 * coefp[0] * (LN2 / (float)GN));
    }
}

extern "C" void kernel_launch(void* const* d_in, const int* in_sizes, int n_in,
                              void* d_out, int out_size, void* d_ws, size_t ws_size,
                              hipStream_t stream) {
    const float* x = (const float*)d_in[0];      // 8192*768 fp32
    const float* coefp = (const float*)d_in[1];  // scalar
    const float* taup = (const float*)d_in[2];   // scalar
    float* out = (float*)d_out;

    char* ws = (char*)d_ws;
    unsigned char* xq = (unsigned char*)ws;              // 6,291,456 B (fp8)
    float* sq = (float*)(ws + 6291456);                  // 32,768 B
    float* pm = (float*)(ws + 6324224);                  // 2,097,152 B
    float* ps = (float*)(ws + 6324224 + 2097152);        // 2,097,152 B
    float* pt = (float*)(ws + 6324224 + 2 * 2097152);    // 2,097,152 B

    prep_kernel<<<GN / 4, 256, 0, stream>>>(x, xq, sq, out);
    sym_gemm_entropy<<<NTILE, 256, 0, stream>>>(xq, sq, taup, pm, ps, pt);
    combine<<<GN / 64, 256, 0, stream>>>(pm, ps, pt, coefp, out);
}

// Round 5
// 140.473 us; speedup vs baseline: 1.0612x; 1.0612x over previous
//
#include <hip/hip_runtime.h>
#include <hip/hip_bf16.h>
#include <hip/hip_fp8.h>
#include <cstdint>
#include <cstddef>

// Problem constants (x = (8192, 768) fp32)
#define GN 8192
#define GD 768           // elements per row; fp8 => 768 bytes per row
#define NB 64            // 128-row blocks
#define NTILE 2080       // NB*(NB+1)/2 triangular tiles
#define KI 12            // 768 / 64 : K-iterations, 64 bytes (one 32x32x64 MFMA) each

#define LOG2E 1.4426950408889634f
#define LN2 0.6931471805599453f

typedef __attribute__((ext_vector_type(4))) float f32x4;
typedef __attribute__((ext_vector_type(16))) float f32x16;
typedef __attribute__((ext_vector_type(4))) int i32x4;
typedef __attribute__((ext_vector_type(8))) int i32x8;

typedef __attribute__((address_space(1))) const unsigned int gu32;
typedef __attribute__((address_space(3))) unsigned int lu32;

#define SHUF8(L, H) __builtin_shufflevector(L, H, 0, 1, 2, 3, 4, 5, 6, 7)
#define Z16 {0.f, 0.f, 0.f, 0.f, 0.f, 0.f, 0.f, 0.f, 0.f, 0.f, 0.f, 0.f, 0.f, 0.f, 0.f, 0.f}
#define MXFMA(A, B, C) __builtin_amdgcn_mfma_scale_f32_32x32x64_f8f6f4( \
    A, B, C, 0, 0, 0, 0x7f7f7f7f, 0, 0x7f7f7f7f)

__device__ __forceinline__ void gl2lds16(const void* g, void* l) {
    // async global->LDS, 16B per lane; LDS dest is wave-uniform base + lane*16
    __builtin_amdgcn_global_load_lds((gu32*)g, (lu32*)l, 16, 0, 0);
}

__device__ __forceinline__ float hexp2(float x) {
    return __builtin_amdgcn_exp2f(x);
}

// DPP rotate within each 16-lane row (VALU pipe, not DS): dpp_ctrl = 0x120|n.
template <int CTRL>
__device__ __forceinline__ float fdpp(float x) {
    return __int_as_float(__builtin_amdgcn_update_dpp(
        0, __float_as_int(x), CTRL, 0xF, 0xF, true));
}
__device__ __forceinline__ float qmax16(float v) {
    v = fmaxf(v, fdpp<0x128>(v));  // row_ror:8
    v = fmaxf(v, fdpp<0x124>(v));  // row_ror:4
    v = fmaxf(v, fdpp<0x122>(v));  // row_ror:2
    v = fmaxf(v, fdpp<0x121>(v));  // row_ror:1
    return v;
}
__device__ __forceinline__ float qsum16(float v) {
    v += fdpp<0x128>(v);
    v += fdpp<0x124>(v);
    v += fdpp<0x122>(v);
    v += fdpp<0x121>(v);
    return v;
}

// ---------------- Kernel 1: fp8 e4m3 quantize + row sum-of-squares of the
// DEQUANTIZED values (sim_ij = -||x^_i - x^_j||^2 - 100*diag exactly) -------
__global__ __launch_bounds__(256) void prep_kernel(const float* __restrict__ x,
                                                   unsigned char* __restrict__ xq,
                                                   float* __restrict__ sq,
                                                   float* __restrict__ out) {
    if (blockIdx.x == 0 && threadIdx.x == 0) out[0] = 0.f;  // for combine's atomics
    const int w = threadIdx.x >> 6, lane = threadIdx.x & 63;
    const int row = blockIdx.x * 4 + w;
    const float4* xr = (const float4*)(x + (size_t)row * GD);
    unsigned int* xqr = (unsigned int*)(xq + (size_t)row * GD);
    float s = 0.f;
#pragma unroll
    for (int i = 0; i < 3; ++i) {
        float4 v = xr[lane + 64 * i];
        unsigned int pk = __builtin_amdgcn_cvt_pk_fp8_f32(v.x, v.y, 0, false);
        pk = __builtin_amdgcn_cvt_pk_fp8_f32(v.z, v.w, pk, true);
        float d0 = __builtin_amdgcn_cvt_f32_fp8(pk, 0);
        float d1 = __builtin_amdgcn_cvt_f32_fp8(pk, 1);
        float d2 = __builtin_amdgcn_cvt_f32_fp8(pk, 2);
        float d3 = __builtin_amdgcn_cvt_f32_fp8(pk, 3);
        s += d0 * d0 + d1 * d1 + d2 * d2 + d3 * d3;
        xqr[lane + 64 * i] = pk;
    }
#pragma unroll
    for (int off = 1; off < 64; off <<= 1) s += __shfl_xor(s, off);
    if (lane == 0) sq[row] = s;
}

// ------- Kernel 2: symmetric triangular tile GEMM (MX-fp8, scale=1.0) + entropy -------
// Round-4 post-mortem: conflict-free layout CONFIRMED (4.28e6 -> 0.29e6);
// A-direct-to-register regressed (exposed VMEM gather latency; +17us stall).
// Round-5:
//  (a) A restored to LDS via gl2lds, SAME proven conflict-free layout as B
//      (identical read shape: per 32-row group of 2KB, granule (r,q) at slot
//      (qlo<<6)|(qhi<<5)|(r4<<4)|(r3<<3)|((r&7)^((qhi<<1)|r4)) ).
//  (b) T3+T4: 3-buffer depth-2 pipeline with COUNTED vmcnt (never 0 in main
//      loop). Per iter: wait vmcnt(4) [own stage k landed] -> raw s_barrier
//      [publish; also proves buf[k+2] readers done, since their ds_reads
//      retired before their MFMAs last iter] -> sched_barrier(0) [no compiler
//      hoist] -> issue stage(k+2) -> ds_read buf[k] -> 4 MFMA. Stage loads
//      get ~2 iterations of latency cover; no vmcnt(0) drain until last iter.
// 32x32x64 operand layout (HW-verified): A/B row = lane&31, k-half = lane>>5
// -> granules {2*hi, 2*hi+1}. C/D: col = lane&31, reg e -> row =
// (e&3) + 8*(e>>2) + 4*(lane>>5).
__global__ __launch_bounds__(256, 3) void sym_gemm_entropy(
    const unsigned char* __restrict__ xq, const float* __restrict__ sq,
    const float* __restrict__ taup, float* __restrict__ pm,
    float* __restrict__ ps, float* __restrict__ pt) {
    __shared__ __align__(16) char lds[49152];  // 3 x [A 8K][B 8K]
    float (*tmrg)[4][3] = (float (*)[4][3])lds;  // aliased; guarded by barrier

    const int tid = threadIdx.x;
    const int lane = tid & 63;
    const int w = tid >> 6;
    const int cl2 = lane & 31, hi = lane >> 5;

    const int b = blockIdx.x;
    int I = (int)((sqrtf(8.0f * (float)b + 1.0f) - 1.0f) * 0.5f);
    while ((I + 1) * (I + 2) / 2 <= b) ++I;
    while (I * (I + 1) / 2 > b) --I;
    const int J = b - I * (I + 1) / 2;
    const int row_base = I * 128;
    const int col_base = J * 128;
    const float taub = (*taup) * LOG2E;  // base-2 scale

    // ---- staging decode: thread t fills slot (t&127) of group (t>>7) (and
    // group (t>>7)+2 via +64*GD). Inverse of the conflict-free layout. ----
    const int sS = tid & 127;
    const int g0S = tid >> 7;  // 0..1
    const int qloS = (sS >> 6) & 1, qhiS = (sS >> 5) & 1;
    const int r4S = (sS >> 4) & 1, r3S = (sS >> 3) & 1;
    const int rlowS = (sS & 7) ^ ((qhiS << 1) | r4S);
    const int rS = (r4S << 4) | (r3S << 3) | rlowS;  // row within 32-row group
    const int qS = (qhiS << 1) | qloS;               // 16B granule 0..3
    const unsigned char* gA = xq + (size_t)(row_base + g0S * 32 + rS) * GD + qS * 16;
    const unsigned char* gB = xq + (size_t)(col_base + g0S * 32 + rS) * GD + qS * 16;

    // ---- fragment read offsets (named scalars; same slot fn for A and B) ----
    const int r4L = (cl2 >> 4) & 1, r3L = (cl2 >> 3) & 1;
    const int bsl = (cl2 & 7) ^ ((hi << 1) | r4L);
    const int s0 = (hi << 5) | (r4L << 4) | (r3L << 3) | bsl;  // qlo=0 slot
    const int offA0 = w * 2048 + (s0 << 4), offA1 = offA0 + 1024;  // A group w
    const int offB00 = 8192 + 0 * 2048 + (s0 << 4), offB01 = offB00 + 1024;
    const int offB10 = 8192 + 1 * 2048 + (s0 << 4), offB11 = offB10 + 1024;
    const int offB20 = 8192 + 2 * 2048 + (s0 << 4), offB21 = offB20 + 1024;
    const int offB30 = 8192 + 3 * 2048 + (s0 << 4), offB31 = offB30 + 1024;

    f32x16 acc0 = Z16, acc1 = Z16, acc2 = Z16, acc3 = Z16;

#define STAGE(BUF, KO)                                                \
    do {                                                              \
        char* bn_ = lds + (BUF) * 16384;                              \
        gl2lds16(gA + (KO), bn_ + tid * 16);                          \
        gl2lds16(gA + (size_t)64 * GD + (KO), bn_ + 4096 + tid * 16); \
        gl2lds16(gB + (KO), bn_ + 8192 + tid * 16);                   \
        gl2lds16(gB + (size_t)64 * GD + (KO), bn_ + 12288 + tid * 16);\
    } while (0)

    // prologue: stage k=0 -> buf0, k=1 -> buf1 (8 loads outstanding)
    STAGE(0, 0);
    STAGE(1, 64);

#pragma unroll
    for (int kk = 0; kk < KI; ++kk) {
        // own stage-k loads landed (keep stage-(k+1) in flight); then publish.
        if (kk < KI - 1)
            asm volatile("s_waitcnt vmcnt(4)" ::: "memory");
        else
            asm volatile("s_waitcnt vmcnt(0)" ::: "memory");
        __builtin_amdgcn_s_barrier();
        __builtin_amdgcn_sched_barrier(0);

        // issue stage k+2 first: full iteration of latency cover
        if (kk + 2 < KI) STAGE((kk + 2) % 3, (kk + 2) * 64);

        // read the 10 fragments of this iter (10 x ds_read_b128)
        const char* Ab = lds + (kk % 3) * 16384;
        i32x4 aL = *(const i32x4*)(Ab + offA0), aH = *(const i32x4*)(Ab + offA1);
        i32x4 b0L = *(const i32x4*)(Ab + offB00), b0H = *(const i32x4*)(Ab + offB01);
        i32x4 b1L = *(const i32x4*)(Ab + offB10), b1H = *(const i32x4*)(Ab + offB11);
        i32x4 b2L = *(const i32x4*)(Ab + offB20), b2H = *(const i32x4*)(Ab + offB21);
        i32x4 b3L = *(const i32x4*)(Ab + offB30), b3H = *(const i32x4*)(Ab + offB31);

        // 4 MX MFMAs (K=64, fmt fp8/fp8, scales = 1.0 -> exact fp8 GEMM)
        i32x8 av = SHUF8(aL, aH);
        acc0 = MXFMA(av, SHUF8(b0L, b0H), acc0);
        acc1 = MXFMA(av, SHUF8(b1L, b1H), acc1);
        acc2 = MXFMA(av, SHUF8(b2L, b2H), acc2);
        acc3 = MXFMA(av, SHUF8(b3L, b3H), acc3);
    }
#undef STAGE

    // ---- split named f32x16 accs into f32x4 quads (constant masks only) ----
    f32x4 pa[4][4];
#define SPLIT16(TJ, A)                                          \
    pa[TJ][0] = __builtin_shufflevector(A, A, 0, 1, 2, 3);      \
    pa[TJ][1] = __builtin_shufflevector(A, A, 4, 5, 6, 7);      \
    pa[TJ][2] = __builtin_shufflevector(A, A, 8, 9, 10, 11);    \
    pa[TJ][3] = __builtin_shufflevector(A, A, 12, 13, 14, 15);
    SPLIT16(0, acc0)
    SPLIT16(1, acc1)
    SPLIT16(2, acc2)
    SPLIT16(3, acc3)
#undef SPLIT16

    // ---------------- epilogue (base-2 state, base-cancelled deltas) ----------------
    const float t2 = 2.f * taub;
    const float pen = 100.f * taub;
    float ar[16];  // -taub * sq[row], indexed [q*4+rg]
#pragma unroll
    for (int q = 0; q < 4; ++q)
#pragma unroll
        for (int rg = 0; rg < 4; ++rg)
            ar[q * 4 + rg] = -taub * sq[row_base + w * 32 + rg + 8 * q + 4 * hi];
    float ac[4];  // -taub * sq[col] for this lane's 4 cols
#pragma unroll
    for (int tj = 0; tj < 4; ++tj) ac[tj] = -taub * sq[col_base + tj * 32 + cl2];

    float* pmJ = pm + (size_t)J * GN;
    float* psJ = ps + (size_t)J * GN;
    float* ptJ = pt + (size_t)J * GN;

    // ---- direct pass: reduce over cols (4 tj in-thread x 32 lanes); the row
    // term is uniform across the reduction -> cancels in d; added once to m ----
#pragma unroll
    for (int q = 0; q < 4; ++q)
#pragma unroll
        for (int rg = 0; rg < 4; ++rg) {
            const int rl = rg + 8 * q + 4 * hi;
            const int rglob = row_base + w * 32 + rl;
            float uu[4];
            float mloc = -1e30f;
            if (I == J) {  // block-uniform: only diagonal tiles carry the penalty
#pragma unroll
                for (int tj = 0; tj < 4; ++tj) {
                    float u = fmaf(t2, pa[tj][q][rg], ac[tj]);
                    if (rglob == col_base + tj * 32 + cl2) u -= pen;
                    uu[tj] = u;
                    mloc = fmaxf(mloc, u);
                }
            } else {
#pragma unroll
                for (int tj = 0; tj < 4; ++tj) {
                    float u = fmaf(t2, pa[tj][q][rg], ac[tj]);
                    uu[tj] = u;
                    mloc = fmaxf(mloc, u);
                }
            }
            mloc = fmaxf(mloc, __shfl_xor(mloc, 16));  // 32-wide max
            mloc = qmax16(mloc);
            float s = 0.f, t = 0.f;
#pragma unroll
            for (int tj = 0; tj < 4; ++tj) {
                float d = uu[tj] - mloc;  // row term cancelled
                float e = hexp2(d);       // bare v_exp_f32
                s += e;
                t += e * d;
            }
            s += __shfl_xor(s, 16);
            t += __shfl_xor(t, 16);
            s = qsum16(s);
            t = qsum16(t);
            if (cl2 == 0) {  // lanes 0 and 32 write disjoint rows
                pmJ[rglob] = mloc + ar[q * 4 + rg];  // base restored once
                psJ[rglob] = s;
                ptJ[rglob] = t;
            }
        }

    // ---- transposed pass: reduce over rows (16 in-thread x 2 hi-halves); col
    // term uniform across the reduction -> cancels in d; added once to m ----
    if (I != J) {  // block-uniform branch
        __syncthreads();  // all K-loop LDS reads done before tmrg aliases the buffer
#pragma unroll
        for (int tj = 0; tj < 4; ++tj) {
            float uu[16];
            float mloc = -1e30f;
#pragma unroll
            for (int q = 0; q < 4; ++q)
#pragma unroll
                for (int rg = 0; rg < 4; ++rg) {
                    float u = fmaf(t2, pa[tj][q][rg], ar[q * 4 + rg]);
                    uu[q * 4 + rg] = u;
                    mloc = fmaxf(mloc, u);
                }
            mloc = fmaxf(mloc, __shfl_xor(mloc, 32));  // combine hi-halves
            float s = 0.f, t = 0.f;
#pragma unroll
            for (int k = 0; k < 16; ++k) {
                float d = uu[k] - mloc;
                float e = hexp2(d);
                s += e;
                t += e * d;
            }
            s += __shfl_xor(s, 32);
            t += __shfl_xor(t, 32);
            if (hi == 0) {
                int c = tj * 32 + cl2;
                tmrg[c][w][0] = mloc + ac[tj];  // col term restored once
                tmrg[c][w][1] = s;
                tmrg[c][w][2] = t;
            }
        }
        __syncthreads();
        if (tid < 128) {
            float m = tmrg[tid][0][0], S = tmrg[tid][0][1], T = tmrg[tid][0][2];
#pragma unroll
            for (int ww = 1; ww < 4; ++ww) {
                float mc = tmrg[tid][ww][0], Sc = tmrg[tid][ww][1], Tc = tmrg[tid][ww][2];
                float mn = fmaxf(m, mc);
                float ea = hexp2(m - mn), eb = hexp2(mc - mn);
                T = (T + (m - mn) * S) * ea + (Tc + (mc - mn) * Sc) * eb;
                S = S * ea + Sc * eb;
                m = mn;
            }
            int c = col_base + tid;
            pm[(size_t)I * GN + c] = m;
            ps[(size_t)I * GN + c] = S;
            pt[(size_t)I * GN + c] = T;
        }
    }
}

// ------- Kernel 3: combine (base-2), coalesced + parallel -------
__global__ __launch_bounds__(256) void combine(const float* __restrict__ pm,
                                               const float* __restrict__ ps,
                                               const float* __restrict__ pt,
                                               const float* __restrict__ coefp,
                                               float* __restrict__ out) {
    const int t = threadIdx.x;
    const int r = t & 63;
    const int chunk = t >> 6;
    const int row = blockIdx.x * 64 + r;
    float m = -1e30f, S = 0.f, T = 0.f;
#pragma unroll
    for (int i = 0; i < 16; ++i) {
        const int c = chunk * 16 + i;
        float mc = pm[(size_t)c * GN + row];
        float Sc = ps[(size_t)c * GN + row];
        float Tc = pt[(size_t)c * GN + row];
        float mn = fmaxf(m, mc);
        float ea = __builtin_amdgcn_exp2f(m - mn), eb = __builtin_amdgcn_exp2f(mc - mn);
        T = (T + (m - mn) * S) * ea + (Tc + (mc - mn) * Sc) * eb;
        S = S * ea + Sc * eb;
        m = mn;
    }
    __shared__ float lm[4][64], lS[4][64], lT[4][64];
    lm[chunk][r] = m;
    lS[chunk][r] = S;
    lT[chunk][r] = T;
    __syncthreads();
    if (t < 64) {
        float M = lm[0][r], Sa = lS[0][r], Ta = lT[0][r];
#pragma unroll
        for (int cc = 1; cc < 4; ++cc) {
            float mc = lm[cc][r], Sc = lS[cc][r], Tc = lT[cc][r];
            float mn = fmaxf(M, mc);
            float ea = __builtin_amdgcn_exp2f(M - mn), eb = __builtin_amdgcn_exp2f(mc - mn);
            Ta = (Ta + (M - mn) * Sa) * ea + (Tc + (mc - mn) * Sc) * eb;
            Sa = Sa * ea + Sc * eb;
            M = mn;
        }
        float ent2 = __log2f(Sa) - Ta / Sa;  // base-2 row entropy (v_log_f32)
#pragma unroll
        for (int off = 1; off < 64; off <<= 1) ent2 += __shfl_xor(ent2, off);
        if (t == 0) atomicAdd(out, ent2 * coefp[0] * (LN2 / (float)GN));
    }
}

extern "C" void kernel_launch(void* const* d_in, const int* in_sizes, int n_in,
                              void* d_out, int out_size, void* d_ws, size_t ws_size,
                              hipStream_t stream) {
    const float* x = (const float*)d_in[0];      // 8192*768 fp32
    const float* coefp = (const float*)d_in[1];  // scalar
    const float* taup = (const float*)d_in[2];   // scalar
    float* out = (float*)d_out;

    char* ws = (char*)d_ws;
    unsigned char* xq = (unsigned char*)ws;              // 6,291,456 B (fp8)
    float* sq = (float*)(ws + 6291456);                  // 32,768 B
    float* pm = (float*)(ws + 6324224);                  // 2,097,152 B
    float* ps = (float*)(ws + 6324224 + 2097152);        // 2,097,152 B
    float* pt = (float*)(ws + 6324224 + 2 * 2097152);    // 2,097,152 B

    prep_kernel<<<GN / 4, 256, 0, stream>>>(x, xq, sq, out);
    sym_gemm_entropy<<<NTILE, 256, 0, stream>>>(xq, sq, taup, pm, ps, pt);
    combine<<<GN / 64, 256, 0, stream>>>(pm, ps, pt, coefp, out);
}